// Round 11
// baseline (778.994 us; speedup 1.0000x reference)
//
#include <hip/hip_runtime.h>
#include <hip/hip_fp16.h>
#include <stdint.h>

// PrunedInt4Linear: y = x @ dequant(q, scales)^T + bias
// Round 11: r10 with the tail off-by-one fixed (loop bound 124 -> 126 so
// slabs 126,127 are staged by the last loop iteration; tail publishes them
// with VMCNT(4)/VMCNT(0)). r10's absmax 6.53 was exactly the 2-missing-slab
// signature -- the fine-phase pipeline discipline itself was race-free.

#define M_DIM 8192
#define N_DIM 11008
#define K_DIM 4096
#define MT_TILES 32            // 8192 / 256
#define NT_TILES 43            // 11008 / 256
#define K_TILES 128            // 4096 / 32
#define SLAB 8192              // shorts per (tile, kt) slab: 256 rows * 32 k

typedef short short8 __attribute__((ext_vector_type(8)));   // 8 bf16
typedef float floatx4 __attribute__((ext_vector_type(4)));

// f32 -> bf16, round-to-nearest-even
__device__ __forceinline__ unsigned short f2bf(float f) {
  union { float f; uint32_t u; } c; c.f = f;
  uint32_t u = c.u;
  return (unsigned short)((u + 0x7FFFu + ((u >> 16) & 1u)) >> 16);
}

__device__ __forceinline__ float load_sc(const void* p, size_t idx, bool is_f32) {
  if (is_f32) return ((const float*)p)[idx];
  return __half2float(((const __half*)p)[idx]);
}

// ---- dtype sniffs (verified rounds 2-9) ----
__device__ __forceinline__ bool sniff_q_is_i32(const void* qv) {
  const int* w = (const int*)qv;
  bool ok = true;
  #pragma unroll
  for (int j = 0; j < 16; ++j) {
    int v = w[j];
    ok = ok && (v == (int)(signed char)(v & 0xFF));
  }
  return ok;
}
__device__ __forceinline__ bool sniff_s_is_f32(const void* sv) {
  const float* f = (const float*)sv;
  bool ok = true;
  #pragma unroll
  for (int j = 0; j < 8; ++j) {
    float v = f[j];
    ok = ok && (v > 4e-4f) && (v < 6e-2f);
  }
  return ok;
}

// async global -> LDS, 16B per lane (dest = wave-uniform base + lane*16)
__device__ __forceinline__ void gload_lds16(const short* g, short* l) {
  __builtin_amdgcn_global_load_lds(
      (const __attribute__((address_space(1))) uint32_t*)g,
      (__attribute__((address_space(3))) uint32_t*)l, 16, 0, 0);
}

// ============ fused prep (r8/r9-verified): W-dequant + x-convert ============
// xh: [mt 32][kt 128][slab]; (r,k) at r*32 + ((k/8) ^ ((r>>1)&3))*8 + (k%8)
// wq: [nt 43][kt 128][slab]; same within-slab swizzle (cols as rows)
__global__ __launch_bounds__(256)
void prep_fused(const float* __restrict__ x, const void* __restrict__ qv,
                const void* __restrict__ sv,
                short* __restrict__ xh, short* __restrict__ wq) {
  const int tid = threadIdx.x;
  int b = blockIdx.x;

  if (b < NT_TILES * 256) {
    // ---- W dequant ----
    const bool q_is_i32 = sniff_q_is_i32(qv);
    const bool s_is_f32 = sniff_s_is_f32(sv);
    const int nt = b >> 8;
    const int rem = b & 255;
    const int kt = rem >> 1, half = rem & 1;
    const int r = half * 128 + (tid >> 1);
    const int s0 = (tid & 1) * 2;
    const int o = nt * 256 + r;
    const int k0 = kt * 32 + s0 * 8;

    const float s = load_sc(sv, (size_t)o * 64 + (kt >> 1), s_is_f32);

    int codes[16];
    if (q_is_i32) {
      const int* qq = (const int*)qv + (size_t)o * K_DIM + k0;
      #pragma unroll
      for (int j = 0; j < 4; ++j) {
        int4 t = ((const int4*)qq)[j];
        codes[j*4+0]=t.x; codes[j*4+1]=t.y; codes[j*4+2]=t.z; codes[j*4+3]=t.w;
      }
    } else {
      union { int4 v; int8_t c[16]; } u;
      u.v = *(const int4*)((const int8_t*)qv + (size_t)o * K_DIM + k0);
      #pragma unroll
      for (int j = 0; j < 16; ++j) codes[j] = (int)u.c[j];
    }

    short8 h0, h1;
    #pragma unroll
    for (int j = 0; j < 8; ++j) h0[j] = f2bf((float)codes[j] * s);
    #pragma unroll
    for (int j = 0; j < 8; ++j) h1[j] = f2bf((float)codes[8 + j] * s);

    const int w = (r >> 1) & 3;
    short* slab = wq + ((size_t)nt * K_TILES + kt) * SLAB;
    *(short8*)&slab[r * 32 + ((s0    ) ^ w) * 8] = h0;
    *(short8*)&slab[r * 32 + ((s0 + 1) ^ w) * 8] = h1;
  } else {
    // ---- x convert ----
    b -= NT_TILES * 256;
    const int mt = b >> 8;
    const int rem = b & 255;
    const int kt = rem >> 1, half = rem & 1;
    const int r = half * 128 + (tid >> 1);
    const int s0 = (tid & 1) * 2;
    const int k0 = kt * 32 + s0 * 8;

    const float4* p = (const float4*)(x + (size_t)(mt * 256 + r) * K_DIM + k0);
    float4 f0 = p[0], f1 = p[1], f2 = p[2], f3 = p[3];
    short8 h0, h1;
    h0[0]=f2bf(f0.x); h0[1]=f2bf(f0.y); h0[2]=f2bf(f0.z); h0[3]=f2bf(f0.w);
    h0[4]=f2bf(f1.x); h0[5]=f2bf(f1.y); h0[6]=f2bf(f1.z); h0[7]=f2bf(f1.w);
    h1[0]=f2bf(f2.x); h1[1]=f2bf(f2.y); h1[2]=f2bf(f2.z); h1[3]=f2bf(f2.w);
    h1[4]=f2bf(f3.x); h1[5]=f2bf(f3.y); h1[6]=f2bf(f3.z); h1[7]=f2bf(f3.w);

    const int w = (r >> 1) & 3;
    short* slab = xh + ((size_t)mt * K_TILES + kt) * SLAB;
    *(short8*)&slab[r * 32 + ((s0    ) ^ w) * 8] = h0;
    *(short8*)&slab[r * 32 + ((s0 + 1) ^ w) * 8] = h1;
  }
}

// ============ GEMM: 256x256, BK=32, 8 waves, fine 4-phase inner loop ========
__global__ __launch_bounds__(512)
void gemm8(const short* __restrict__ xh, const short* __restrict__ wq,
           const void* __restrict__ sv, const void* __restrict__ bv,
           float* __restrict__ C) {
  __shared__ __align__(16) short lds[4 * 2 * SLAB];   // 128 KiB: 4 bufs x (A,B)

  const bool s_is_f32 = sniff_s_is_f32(sv);   // bias dtype tracks scales

  const int tid  = threadIdx.x;
  const int lane = tid & 63;
  const int wid  = tid >> 6;                  // 8 waves
  const int wm = wid >> 2, wn = wid & 3;      // 2x4 -> 128x64 out per wave
  const int lr = lane & 15, lk = lane >> 4;

  // nt-major dispatch (r6/r8-verified: FETCH 1.5G->0.55G)
  const int bid = blockIdx.x;
  const int xcd = bid & 7;
  const int seq = bid >> 3;                   // [0,172)
  const int nt  = seq >> 2;                   // [0,43)
  const int mt  = xcd * 4 + (seq & 3);        // [0,32)

  const short* Aslab = xh + (size_t)mt * K_TILES * SLAB;
  const short* Bslab = wq + (size_t)nt * K_TILES * SLAB;

  // fragment LDS offsets (r4/r6-verified, 0 conflicts); A split in row-halves
  const int swz8 = (lk ^ ((lr >> 1) & 3)) << 3;
  int aoff[2][4], boff[4];
  #pragma unroll
  for (int h = 0; h < 2; ++h)
    #pragma unroll
    for (int mi = 0; mi < 4; ++mi)
      aoff[h][mi] = (wm * 128 + h * 64 + mi * 16 + lr) * 32 + swz8;
  #pragma unroll
  for (int ni = 0; ni < 4; ++ni) boff[ni] = (wn * 64 + ni * 16 + lr) * 32 + swz8;

  floatx4 acc[8][4];
  #pragma unroll
  for (int i = 0; i < 8; ++i)
    #pragma unroll
    for (int j = 0; j < 4; ++j)
      acc[i][j] = (floatx4){0.f, 0.f, 0.f, 0.f};

  short8 fa[4], fb[4];   // A row-half + B (B reused across the two halves)

#define FENCE asm volatile("" ::: "memory")
#define VMCNT(n) asm volatile("s_waitcnt vmcnt(" #n ")" ::: "memory")
#define BARRIER do { FENCE; __builtin_amdgcn_s_barrier(); FENCE; } while (0)

#define STAGE_A(t) do {                                                 \
    const short* gA_ = Aslab + (size_t)(t) * SLAB;                      \
    short* lA_ = &lds[((t) & 3) * (2 * SLAB)];                          \
    gload_lds16(gA_ + tid * 8,        lA_ + tid * 8);                   \
    gload_lds16(gA_ + 4096 + tid * 8, lA_ + 4096 + tid * 8);            \
    FENCE;                                                              \
  } while (0)

#define STAGE_B(t) do {                                                 \
    const short* gB_ = Bslab + (size_t)(t) * SLAB;                      \
    short* lB_ = &lds[((t) & 3) * (2 * SLAB)] + SLAB;                   \
    gload_lds16(gB_ + tid * 8,        lB_ + tid * 8);                   \
    gload_lds16(gB_ + 4096 + tid * 8, lB_ + 4096 + tid * 8);            \
    FENCE;                                                              \
  } while (0)

#define LOADA(h, t) do {                                                \
    const short* lA_ = &lds[((t) & 3) * (2 * SLAB)];                    \
    _Pragma("unroll")                                                   \
    for (int mi = 0; mi < 4; ++mi) fa[mi] = *(const short8*)&lA_[aoff[h][mi]]; \
  } while (0)

#define LOADB(t) do {                                                   \
    const short* lB_ = &lds[((t) & 3) * (2 * SLAB)] + SLAB;             \
    _Pragma("unroll")                                                   \
    for (int ni = 0; ni < 4; ++ni) fb[ni] = *(const short8*)&lB_[boff[ni]]; \
  } while (0)

#define MFMA_HALF(h) do {                                               \
    __builtin_amdgcn_s_setprio(1);                                      \
    _Pragma("unroll")                                                   \
    for (int mi = 0; mi < 4; ++mi)                                      \
      _Pragma("unroll")                                                 \
      for (int ni = 0; ni < 4; ++ni)                                    \
        acc[(h) * 4 + mi][ni] = __builtin_amdgcn_mfma_f32_16x16x32_bf16( \
            fa[mi], fb[ni], acc[(h) * 4 + mi][ni], 0, 0, 0);            \
    __builtin_amdgcn_s_setprio(0);                                      \
  } while (0)

  // prologue: stage slabs 0,1 -> FIFO [0A,0B,1A,1B] = 8 loads
  STAGE_A(0); STAGE_B(0); STAGE_A(1); STAGE_B(1);

  // Main loop: 2 slabs / iter, 4 phases; counted VMCNT(4) at two publish
  // points. FIFO at top: [ktA,ktB,kt+1A,kt+1B] (8) -- VMCNT(4) retires
  // ktA,ktB (issued >= 1 full iter ago). Stages write slots (kt+2)&3,
  // (kt+3)&3, disjoint from read slots kt&3,(kt+1)&3.
  // Last iteration kt=124 computes 124,125 and stages 126,127 (r10 bug:
  // bound was 124, leaving slabs 126,127 unstaged -> absmax 6.53).
  for (int kt = 0; kt < 126; kt += 2) {
    VMCNT(4);
    BARRIER;                    // publish slab kt
    // ph0: A-half0(kt) + B(kt) reads fly during barrier convergence
    LOADA(0, kt);
    LOADB(kt);
    STAGE_A(kt + 2);
    BARRIER;
    MFMA_HALF(0);
    BARRIER;
    // ph1: A-half1(kt); B reused in regs
    LOADA(1, kt);
    STAGE_B(kt + 2);
    BARRIER;
    MFMA_HALF(1);
    VMCNT(4);
    BARRIER;                    // publish slab kt+1 (retires kt+1A,kt+1B)
    // ph2
    LOADA(0, kt + 1);
    LOADB(kt + 1);
    STAGE_A(kt + 3);
    BARRIER;
    MFMA_HALF(0);
    BARRIER;
    // ph3
    LOADA(1, kt + 1);
    STAGE_B(kt + 3);
    BARRIER;
    MFMA_HALF(1);
    // loop top supplies VMCNT + publish barrier
  }

  // after kt=124 iter: outstanding FIFO = [A126,B126,A127,B127]
  VMCNT(4);
  BARRIER;                      // publish 126 (retires A126,B126)
  LOADA(0, 126); LOADB(126);
  BARRIER;
  MFMA_HALF(0);
  BARRIER;
  LOADA(1, 126);
  BARRIER;
  MFMA_HALF(1);
  VMCNT(0);
  BARRIER;                      // publish 127
  LOADA(0, 127); LOADB(127);
  BARRIER;
  MFMA_HALF(0);
  BARRIER;
  LOADA(1, 127);
  BARRIER;
  MFMA_HALF(1);

#undef STAGE_A
#undef STAGE_B
#undef LOADA
#undef LOADB
#undef MFMA_HALF
#undef FENCE
#undef VMCNT
#undef BARRIER

  // epilogue: C/D layout col = lane&15, row = (lane>>4)*4 + reg (verified)
  #pragma unroll
  for (int ni = 0; ni < 4; ++ni) {
    const int col = nt * 256 + wn * 64 + ni * 16 + lr;
    const float bvf = load_sc(bv, (size_t)col, s_is_f32);
    #pragma unroll
    for (int mi = 0; mi < 8; ++mi) {
      const int rbase = mt * 256 + wm * 128 + mi * 16 + lk * 4;
      #pragma unroll
      for (int rr = 0; rr < 4; ++rr)
        C[(size_t)(rbase + rr) * N_DIM + col] = acc[mi][ni][rr] + bvf;
    }
  }
}

// ============ fallback: round-2-verified fully fused kernel ============
__global__ __launch_bounds__(256)
void gemm_fused(const float* __restrict__ x, const void* __restrict__ qv,
                const void* __restrict__ sv, const void* __restrict__ bv,
                float* __restrict__ C) {
  __shared__ __align__(16) short As[128 * 64];
  __shared__ __align__(16) short Bs[128 * 64];

  const bool q_is_i32 = sniff_q_is_i32(qv);
  const bool s_is_f32 = sniff_s_is_f32(sv);

  const int tid  = threadIdx.x;
  const int lane = tid & 63;
  const int wid  = tid >> 6;
  const int wm = wid >> 1, wn = wid & 1;
  const int lr = lane & 15, lk = lane >> 4;

  const int nwg = gridDim.x;
  const int cpx = nwg >> 3;
  const int bid = blockIdx.x;
  const int swz = (bid & 7) * cpx + (bid >> 3);
  const int per_g = 4 * 86;
  const int g = swz / per_g;
  const int r = swz - g * per_g;
  const int mt = (g << 2) + (r & 3);
  const int nt = r >> 2;

  const int row0 = mt * 128;
  const int col0 = nt * 128;

  floatx4 acc[4][4];
  #pragma unroll
  for (int i = 0; i < 4; ++i)
    #pragma unroll
    for (int j = 0; j < 4; ++j)
      acc[i][j] = (floatx4){0.f, 0.f, 0.f, 0.f};

  for (int kt = 0; kt < K_DIM / 64; ++kt) {
    const int k0 = kt * 64;
    #pragma unroll
    for (int i = 0; i < 4; ++i) {
      const int cid = i * 256 + tid;
      const int arow = cid >> 3, ac = (cid & 7) << 3;
      const float4* p = (const float4*)(x + (size_t)(row0 + arow) * K_DIM + k0 + ac);
      float4 a = p[0], b = p[1];
      short8 h;
      h[0]=f2bf(a.x); h[1]=f2bf(a.y); h[2]=f2bf(a.z); h[3]=f2bf(a.w);
      h[4]=f2bf(b.x); h[5]=f2bf(b.y); h[6]=f2bf(b.z); h[7]=f2bf(b.w);
      *(short8*)&As[arow * 64 + ac] = h;
    }
    #pragma unroll
    for (int i = 0; i < 2; ++i) {
      const int cid = i * 256 + tid;
      const int brow = cid >> 2, bc = (cid & 3) << 4;
      const float s = load_sc(sv, (size_t)(col0 + brow) * 64 + kt, s_is_f32);
      int codes[16];
      if (q_is_i32) {
        const int* qq = (const int*)qv + (size_t)(col0 + brow) * K_DIM + k0 + bc;
        #pragma unroll
        for (int j = 0; j < 4; ++j) {
          int4 t = ((const int4*)qq)[j];
          codes[j*4+0]=t.x; codes[j*4+1]=t.y; codes[j*4+2]=t.z; codes[j*4+3]=t.w;
        }
      } else {
        union { int4 v; int8_t c[16]; } u;
        u.v = *(const int4*)((const int8_t*)qv + (size_t)(col0 + brow) * K_DIM + k0 + bc);
        #pragma unroll
        for (int j = 0; j < 16; ++j) codes[j] = (int)u.c[j];
      }
      short8 h0, h1;
      #pragma unroll
      for (int j = 0; j < 8; ++j) h0[j] = f2bf((float)codes[j] * s);
      #pragma unroll
      for (int j = 0; j < 8; ++j) h1[j] = f2bf((float)codes[8 + j] * s);
      *(short8*)&Bs[brow * 64 + bc]     = h0;
      *(short8*)&Bs[brow * 64 + bc + 8] = h1;
    }
    __syncthreads();
    #pragma unroll
    for (int ks = 0; ks < 2; ++ks) {
      short8 a[4], b[4];
      #pragma unroll
      for (int mi = 0; mi < 4; ++mi)
        a[mi] = *(const short8*)&As[(wm * 64 + mi * 16 + lr) * 64 + ks * 32 + lk * 8];
      #pragma unroll
      for (int ni = 0; ni < 4; ++ni)
        b[ni] = *(const short8*)&Bs[(wn * 64 + ni * 16 + lr) * 64 + ks * 32 + lk * 8];
      #pragma unroll
      for (int mi = 0; mi < 4; ++mi)
        #pragma unroll
        for (int ni = 0; ni < 4; ++ni)
          acc[mi][ni] = __builtin_amdgcn_mfma_f32_16x16x32_bf16(
              a[mi], b[ni], acc[mi][ni], 0, 0, 0);
    }
    __syncthreads();
  }

  #pragma unroll
  for (int ni = 0; ni < 4; ++ni) {
    const int col = col0 + wn * 64 + ni * 16 + lr;
    const float bvf = load_sc(bv, (size_t)col, s_is_f32);
    #pragma unroll
    for (int mi = 0; mi < 4; ++mi) {
      const int rbase = row0 + wm * 64 + mi * 16 + lk * 4;
      #pragma unroll
      for (int rr = 0; rr < 4; ++rr)
        C[(size_t)(rbase + rr) * N_DIM + col] = acc[mi][ni][rr] + bvf;
    }
  }
}

extern "C" void kernel_launch(void* const* d_in, const int* in_sizes, int n_in,
                              void* d_out, int out_size, void* d_ws, size_t ws_size,
                              hipStream_t stream) {
  const float* x  = (const float*)d_in[0];
  const void*  q  = (const void*)d_in[1];
  const void*  sc = (const void*)d_in[2];
  const void*  bs = (const void*)d_in[3];
  float* y = (float*)d_out;
  (void)in_sizes; (void)n_in; (void)out_size;

  const size_t xh_bytes = (size_t)M_DIM * K_DIM * 2;   // 64 MiB
  const size_t wq_bytes = (size_t)N_DIM * K_DIM * 2;   // ~86 MiB

  if (ws_size >= xh_bytes + wq_bytes) {   // confirmed available (r3-r9)
    short* xh = (short*)d_ws;
    short* wq = (short*)((char*)d_ws + xh_bytes);
    prep_fused<<<NT_TILES * 256 + MT_TILES * 256, dim3(256), 0, stream>>>(
        x, q, sc, xh, wq);
    gemm8<<<MT_TILES * NT_TILES, dim3(512), 0, stream>>>(xh, wq, sc, bs, y);
  } else {
    gemm_fused<<<(M_DIM / 128) * (N_DIM / 128), dim3(256), 0, stream>>>(x, q, sc, bs, y);
  }
}

// Round 12
// 760.370 us; speedup vs baseline: 1.0245x; 1.0245x over previous
//
#include <hip/hip_runtime.h>
#include <hip/hip_fp16.h>
#include <stdint.h>

// PrunedInt4Linear: y = x @ dequant(q, scales)^T + bias
// Round 12: r8's coarse 1-barrier/tile loop, but with NON-DRAINING sync:
// bare "s_waitcnt vmcnt(N)" (no memory clobber) + sched_barrier(0) pins,
// raw s_barrier. Theory: the old asm-"memory" FENCEs made the waitcnt pass
// conservatively drain vmcnt at every barrier (mayLoad|mayStore on the asm),
// nullifying the counted-vmcnt pipeline across r6-r11.

#define M_DIM 8192
#define N_DIM 11008
#define K_DIM 4096
#define MT_TILES 32            // 8192 / 256
#define NT_TILES 43            // 11008 / 256
#define K_TILES 128            // 4096 / 32
#define SLAB 8192              // shorts per (tile, kt) slab: 256 rows * 32 k

typedef short short8 __attribute__((ext_vector_type(8)));   // 8 bf16
typedef float floatx4 __attribute__((ext_vector_type(4)));

// f32 -> bf16, round-to-nearest-even
__device__ __forceinline__ unsigned short f2bf(float f) {
  union { float f; uint32_t u; } c; c.f = f;
  uint32_t u = c.u;
  return (unsigned short)((u + 0x7FFFu + ((u >> 16) & 1u)) >> 16);
}

__device__ __forceinline__ float load_sc(const void* p, size_t idx, bool is_f32) {
  if (is_f32) return ((const float*)p)[idx];
  return __half2float(((const __half*)p)[idx]);
}

// ---- dtype sniffs (verified rounds 2-11) ----
__device__ __forceinline__ bool sniff_q_is_i32(const void* qv) {
  const int* w = (const int*)qv;
  bool ok = true;
  #pragma unroll
  for (int j = 0; j < 16; ++j) {
    int v = w[j];
    ok = ok && (v == (int)(signed char)(v & 0xFF));
  }
  return ok;
}
__device__ __forceinline__ bool sniff_s_is_f32(const void* sv) {
  const float* f = (const float*)sv;
  bool ok = true;
  #pragma unroll
  for (int j = 0; j < 8; ++j) {
    float v = f[j];
    ok = ok && (v > 4e-4f) && (v < 6e-2f);
  }
  return ok;
}

// async global -> LDS, 16B per lane (dest = wave-uniform base + lane*16)
__device__ __forceinline__ void gload_lds16(const short* g, short* l) {
  __builtin_amdgcn_global_load_lds(
      (const __attribute__((address_space(1))) uint32_t*)g,
      (__attribute__((address_space(3))) uint32_t*)l, 16, 0, 0);
}

// ============ fused prep (r8-verified): W-dequant + x-convert ============
// xh: [mt 32][kt 128][slab]; (r,k) at r*32 + ((k/8) ^ ((r>>1)&3))*8 + (k%8)
// wq: [nt 43][kt 128][slab]; same within-slab swizzle (cols as rows)
__global__ __launch_bounds__(256)
void prep_fused(const float* __restrict__ x, const void* __restrict__ qv,
                const void* __restrict__ sv,
                short* __restrict__ xh, short* __restrict__ wq) {
  const int tid = threadIdx.x;
  int b = blockIdx.x;

  if (b < NT_TILES * 256) {
    // ---- W dequant ----
    const bool q_is_i32 = sniff_q_is_i32(qv);
    const bool s_is_f32 = sniff_s_is_f32(sv);
    const int nt = b >> 8;
    const int rem = b & 255;
    const int kt = rem >> 1, half = rem & 1;
    const int r = half * 128 + (tid >> 1);
    const int s0 = (tid & 1) * 2;
    const int o = nt * 256 + r;
    const int k0 = kt * 32 + s0 * 8;

    const float s = load_sc(sv, (size_t)o * 64 + (kt >> 1), s_is_f32);

    int codes[16];
    if (q_is_i32) {
      const int* qq = (const int*)qv + (size_t)o * K_DIM + k0;
      #pragma unroll
      for (int j = 0; j < 4; ++j) {
        int4 t = ((const int4*)qq)[j];
        codes[j*4+0]=t.x; codes[j*4+1]=t.y; codes[j*4+2]=t.z; codes[j*4+3]=t.w;
      }
    } else {
      union { int4 v; int8_t c[16]; } u;
      u.v = *(const int4*)((const int8_t*)qv + (size_t)o * K_DIM + k0);
      #pragma unroll
      for (int j = 0; j < 16; ++j) codes[j] = (int)u.c[j];
    }

    short8 h0, h1;
    #pragma unroll
    for (int j = 0; j < 8; ++j) h0[j] = f2bf((float)codes[j] * s);
    #pragma unroll
    for (int j = 0; j < 8; ++j) h1[j] = f2bf((float)codes[8 + j] * s);

    const int w = (r >> 1) & 3;
    short* slab = wq + ((size_t)nt * K_TILES + kt) * SLAB;
    *(short8*)&slab[r * 32 + ((s0    ) ^ w) * 8] = h0;
    *(short8*)&slab[r * 32 + ((s0 + 1) ^ w) * 8] = h1;
  } else {
    // ---- x convert ----
    b -= NT_TILES * 256;
    const int mt = b >> 8;
    const int rem = b & 255;
    const int kt = rem >> 1, half = rem & 1;
    const int r = half * 128 + (tid >> 1);
    const int s0 = (tid & 1) * 2;
    const int k0 = kt * 32 + s0 * 8;

    const float4* p = (const float4*)(x + (size_t)(mt * 256 + r) * K_DIM + k0);
    float4 f0 = p[0], f1 = p[1], f2 = p[2], f3 = p[3];
    short8 h0, h1;
    h0[0]=f2bf(f0.x); h0[1]=f2bf(f0.y); h0[2]=f2bf(f0.z); h0[3]=f2bf(f0.w);
    h0[4]=f2bf(f1.x); h0[5]=f2bf(f1.y); h0[6]=f2bf(f1.z); h0[7]=f2bf(f1.w);
    h1[0]=f2bf(f2.x); h1[1]=f2bf(f2.y); h1[2]=f2bf(f2.z); h1[3]=f2bf(f2.w);
    h1[4]=f2bf(f3.x); h1[5]=f2bf(f3.y); h1[6]=f2bf(f3.z); h1[7]=f2bf(f3.w);

    const int w = (r >> 1) & 3;
    short* slab = xh + ((size_t)mt * K_TILES + kt) * SLAB;
    *(short8*)&slab[r * 32 + ((s0    ) ^ w) * 8] = h0;
    *(short8*)&slab[r * 32 + ((s0 + 1) ^ w) * 8] = h1;
  }
}

// ============ GEMM: 256x256, BK=32, 8 waves; r8 loop + non-draining sync ====
__global__ __launch_bounds__(512)
void gemm8(const short* __restrict__ xh, const short* __restrict__ wq,
           const void* __restrict__ sv, const void* __restrict__ bv,
           float* __restrict__ C) {
  __shared__ __align__(16) short lds[4 * 2 * SLAB];   // 128 KiB: 4 bufs x (A,B)

  const bool s_is_f32 = sniff_s_is_f32(sv);   // bias dtype tracks scales

  const int tid  = threadIdx.x;
  const int lane = tid & 63;
  const int wid  = tid >> 6;                  // 8 waves
  const int wm = wid >> 2, wn = wid & 3;      // 2x4 -> 128x64 out per wave
  const int lr = lane & 15, lk = lane >> 4;

  // nt-major dispatch (r6/r8-verified: FETCH 1.5G->0.55G)
  const int bid = blockIdx.x;
  const int xcd = bid & 7;
  const int seq = bid >> 3;                   // [0,172)
  const int nt  = seq >> 2;                   // [0,43)
  const int mt  = xcd * 4 + (seq & 3);        // [0,32)

  const short* Aslab = xh + (size_t)mt * K_TILES * SLAB;
  const short* Bslab = wq + (size_t)nt * K_TILES * SLAB;

  // fragment LDS offsets (r4/r6-verified, 0 conflicts)
  const int swz8 = (lk ^ ((lr >> 1) & 3)) << 3;
  int aoff[8], boff[4];
  #pragma unroll
  for (int mi = 0; mi < 8; ++mi) aoff[mi] = (wm * 128 + mi * 16 + lr) * 32 + swz8;
  #pragma unroll
  for (int ni = 0; ni < 4; ++ni) boff[ni] = (wn * 64 + ni * 16 + lr) * 32 + swz8;

  floatx4 acc[8][4];
  #pragma unroll
  for (int i = 0; i < 8; ++i)
    #pragma unroll
    for (int j = 0; j < 4; ++j)
      acc[i][j] = (floatx4){0.f, 0.f, 0.f, 0.f};

  short8 fa[8], fb[4], ga[8], gb[4];   // two named frag sets (rule #20)

#define STAGE(t) do {                                                   \
    const short* gA_ = Aslab + (size_t)(t) * SLAB;                      \
    const short* gB_ = Bslab + (size_t)(t) * SLAB;                      \
    short* lA_ = &lds[((t) & 3) * (2 * SLAB)];                          \
    short* lB_ = lA_ + SLAB;                                            \
    gload_lds16(gA_ + tid * 8,        lA_ + tid * 8);                   \
    gload_lds16(gA_ + 4096 + tid * 8, lA_ + 4096 + tid * 8);            \
    gload_lds16(gB_ + tid * 8,        lB_ + tid * 8);                   \
    gload_lds16(gB_ + 4096 + tid * 8, lB_ + 4096 + tid * 8);            \
  } while (0)

#define LOADF(da, db, t) do {                                           \
    const short* lA_ = &lds[((t) & 3) * (2 * SLAB)];                    \
    const short* lB_ = lA_ + SLAB;                                      \
    _Pragma("unroll")                                                   \
    for (int mi = 0; mi < 8; ++mi) da[mi] = *(const short8*)&lA_[aoff[mi]]; \
    _Pragma("unroll")                                                   \
    for (int ni = 0; ni < 4; ++ni) db[ni] = *(const short8*)&lB_[boff[ni]]; \
  } while (0)

#define DOMFMA(sa, sb) do {                                             \
    __builtin_amdgcn_s_setprio(1);                                      \
    _Pragma("unroll")                                                   \
    for (int mi = 0; mi < 8; ++mi)                                      \
      _Pragma("unroll")                                                 \
      for (int ni = 0; ni < 4; ++ni)                                    \
        acc[mi][ni] = __builtin_amdgcn_mfma_f32_16x16x32_bf16(          \
            sa[mi], sb[ni], acc[mi][ni], 0, 0, 0);                      \
    __builtin_amdgcn_s_setprio(0);                                      \
  } while (0)

// Non-draining sync (rule #18): bare counted waitcnt (NO memory clobber --
// a "memory" clobber sets mayLoad|mayStore and makes the waitcnt pass drain
// counters conservatively), ordering pinned with sched_barrier(0).
#define SBAR __builtin_amdgcn_sched_barrier(0)
#define VMCNT(n) do { asm volatile("s_waitcnt vmcnt(" #n ")"); SBAR; } while (0)
#define BARRIER do { SBAR; __builtin_amdgcn_s_barrier(); SBAR; } while (0)

  // prologue: stage 3 tiles (12 loads/wave outstanding); publish+read tile 0
  STAGE(0); STAGE(1); STAGE(2);
  VMCNT(8);                    // own tile-0 loads retired
  BARRIER;                     // tile 0 published to all waves
  LOADF(fa, fb, 0);

  // Steady state, 2 tiles per loop iter, ONE barrier per tile (r6/r8-proven
  // publish-then-read order; sched_barrier pins keep STAGE/LOADF in-region).
  for (int kt = 0; kt < 124; kt += 2) {
    VMCNT(4);
    BARRIER;
    STAGE(kt + 3);
    LOADF(ga, gb, kt + 1);
    DOMFMA(fa, fb);            // tile kt
    VMCNT(4);
    BARRIER;
    STAGE(kt + 4);
    LOADF(fa, fb, kt + 2);
    DOMFMA(ga, gb);            // tile kt+1
  }

  // tail: staged through 126; fa holds tile 124.
  VMCNT(4);                    // retire 125
  BARRIER;
  STAGE(127);
  LOADF(ga, gb, 125);
  DOMFMA(fa, fb);              // 124
  VMCNT(4);                    // retire 126
  BARRIER;
  LOADF(fa, fb, 126);
  DOMFMA(ga, gb);              // 125
  VMCNT(0);                    // retire 127
  BARRIER;
  LOADF(ga, gb, 127);
  DOMFMA(fa, fb);              // 126
  DOMFMA(ga, gb);              // 127

#undef STAGE
#undef LOADF
#undef DOMFMA
#undef SBAR
#undef VMCNT
#undef BARRIER

  // epilogue: C/D layout col = lane&15, row = (lane>>4)*4 + reg (verified)
  #pragma unroll
  for (int ni = 0; ni < 4; ++ni) {
    const int col = nt * 256 + wn * 64 + ni * 16 + lr;
    const float bvf = load_sc(bv, (size_t)col, s_is_f32);
    #pragma unroll
    for (int mi = 0; mi < 8; ++mi) {
      const int rbase = mt * 256 + wm * 128 + mi * 16 + lk * 4;
      #pragma unroll
      for (int rr = 0; rr < 4; ++rr)
        C[(size_t)(rbase + rr) * N_DIM + col] = acc[mi][ni][rr] + bvf;
    }
  }
}

// ============ fallback: round-2-verified fully fused kernel ============
__global__ __launch_bounds__(256)
void gemm_fused(const float* __restrict__ x, const void* __restrict__ qv,
                const void* __restrict__ sv, const void* __restrict__ bv,
                float* __restrict__ C) {
  __shared__ __align__(16) short As[128 * 64];
  __shared__ __align__(16) short Bs[128 * 64];

  const bool q_is_i32 = sniff_q_is_i32(qv);
  const bool s_is_f32 = sniff_s_is_f32(sv);

  const int tid  = threadIdx.x;
  const int lane = tid & 63;
  const int wid  = tid >> 6;
  const int wm = wid >> 1, wn = wid & 1;
  const int lr = lane & 15, lk = lane >> 4;

  const int nwg = gridDim.x;
  const int cpx = nwg >> 3;
  const int bid = blockIdx.x;
  const int swz = (bid & 7) * cpx + (bid >> 3);
  const int per_g = 4 * 86;
  const int g = swz / per_g;
  const int r = swz - g * per_g;
  const int mt = (g << 2) + (r & 3);
  const int nt = r >> 2;

  const int row0 = mt * 128;
  const int col0 = nt * 128;

  floatx4 acc[4][4];
  #pragma unroll
  for (int i = 0; i < 4; ++i)
    #pragma unroll
    for (int j = 0; j < 4; ++j)
      acc[i][j] = (floatx4){0.f, 0.f, 0.f, 0.f};

  for (int kt = 0; kt < K_DIM / 64; ++kt) {
    const int k0 = kt * 64;
    #pragma unroll
    for (int i = 0; i < 4; ++i) {
      const int cid = i * 256 + tid;
      const int arow = cid >> 3, ac = (cid & 7) << 3;
      const float4* p = (const float4*)(x + (size_t)(row0 + arow) * K_DIM + k0 + ac);
      float4 a = p[0], b = p[1];
      short8 h;
      h[0]=f2bf(a.x); h[1]=f2bf(a.y); h[2]=f2bf(a.z); h[3]=f2bf(a.w);
      h[4]=f2bf(b.x); h[5]=f2bf(b.y); h[6]=f2bf(b.z); h[7]=f2bf(b.w);
      *(short8*)&As[arow * 64 + ac] = h;
    }
    #pragma unroll
    for (int i = 0; i < 2; ++i) {
      const int cid = i * 256 + tid;
      const int brow = cid >> 2, bc = (cid & 3) << 4;
      const float s = load_sc(sv, (size_t)(col0 + brow) * 64 + kt, s_is_f32);
      int codes[16];
      if (q_is_i32) {
        const int* qq = (const int*)qv + (size_t)(col0 + brow) * K_DIM + k0 + bc;
        #pragma unroll
        for (int j = 0; j < 4; ++j) {
          int4 t = ((const int4*)qq)[j];
          codes[j*4+0]=t.x; codes[j*4+1]=t.y; codes[j*4+2]=t.z; codes[j*4+3]=t.w;
        }
      } else {
        union { int4 v; int8_t c[16]; } u;
        u.v = *(const int4*)((const int8_t*)qv + (size_t)(col0 + brow) * K_DIM + k0 + bc);
        #pragma unroll
        for (int j = 0; j < 16; ++j) codes[j] = (int)u.c[j];
      }
      short8 h0, h1;
      #pragma unroll
      for (int j = 0; j < 8; ++j) h0[j] = f2bf((float)codes[j] * s);
      #pragma unroll
      for (int j = 0; j < 8; ++j) h1[j] = f2bf((float)codes[8 + j] * s);
      *(short8*)&Bs[brow * 64 + bc]     = h0;
      *(short8*)&Bs[brow * 64 + bc + 8] = h1;
    }
    __syncthreads();
    #pragma unroll
    for (int ks = 0; ks < 2; ++ks) {
      short8 a[4], b[4];
      #pragma unroll
      for (int mi = 0; mi < 4; ++mi)
        a[mi] = *(const short8*)&As[(wm * 64 + mi * 16 + lr) * 64 + ks * 32 + lk * 8];
      #pragma unroll
      for (int ni = 0; ni < 4; ++ni)
        b[ni] = *(const short8*)&Bs[(wn * 64 + ni * 16 + lr) * 64 + ks * 32 + lk * 8];
      #pragma unroll
      for (int mi = 0; mi < 4; ++mi)
        #pragma unroll
        for (int ni = 0; ni < 4; ++ni)
          acc[mi][ni] = __builtin_amdgcn_mfma_f32_16x16x32_bf16(
              a[mi], b[ni], acc[mi][ni], 0, 0, 0);
    }
    __syncthreads();
  }

  #pragma unroll
  for (int ni = 0; ni < 4; ++ni) {
    const int col = col0 + wn * 64 + ni * 16 + lr;
    const float bvf = load_sc(bv, (size_t)col, s_is_f32);
    #pragma unroll
    for (int mi = 0; mi < 4; ++mi) {
      const int rbase = row0 + wm * 64 + mi * 16 + lk * 4;
      #pragma unroll
      for (int rr = 0; rr < 4; ++rr)
        C[(size_t)(rbase + rr) * N_DIM + col] = acc[mi][ni][rr] + bvf;
    }
  }
}

extern "C" void kernel_launch(void* const* d_in, const int* in_sizes, int n_in,
                              void* d_out, int out_size, void* d_ws, size_t ws_size,
                              hipStream_t stream) {
  const float* x  = (const float*)d_in[0];
  const void*  q  = (const void*)d_in[1];
  const void*  sc = (const void*)d_in[2];
  const void*  bs = (const void*)d_in[3];
  float* y = (float*)d_out;
  (void)in_sizes; (void)n_in; (void)out_size;

  const size_t xh_bytes = (size_t)M_DIM * K_DIM * 2;   // 64 MiB
  const size_t wq_bytes = (size_t)N_DIM * K_DIM * 2;   // ~86 MiB

  if (ws_size >= xh_bytes + wq_bytes) {   // confirmed available (r3-r11)
    short* xh = (short*)d_ws;
    short* wq = (short*)((char*)d_ws + xh_bytes);
    prep_fused<<<NT_TILES * 256 + MT_TILES * 256, dim3(256), 0, stream>>>(
        x, q, sc, xh, wq);
    gemm8<<<MT_TILES * NT_TILES, dim3(512), 0, stream>>>(xh, wq, sc, bs, y);
  } else {
    gemm_fused<<<(M_DIM / 128) * (N_DIM / 128), dim3(256), 0, stream>>>(x, q, sc, bs, y);
  }
}

// Round 13
// 752.151 us; speedup vs baseline: 1.0357x; 1.0109x over previous
//
#include <hip/hip_runtime.h>
#include <hip/hip_fp16.h>
#include <stdint.h>

// PrunedInt4Linear: y = x @ dequant(q, scales)^T + bias
// Round 13: faithful m201 8-phase port. BK=64, 2-deep LDS double-buffer
// (128 KiB), 8 phases per 2 K-tiles, 1 half-tile stage per phase,
// lgkmcnt(0) after each pre-MFMA barrier, 16 MFMA (one C-quadrant) per
// phase, counted VMCNT(4) at phases 4 and 8 only. Quadrant register sets:
// a (one m-half), b0/b1 (both n-halves) -> reads 12/4/8/0 per phase.

#define M_DIM 8192
#define N_DIM 11008
#define K_DIM 4096
#define MT_TILES 32            // 8192 / 256
#define NT_TILES 43            // 11008 / 256
#define KT64 64                // K-tiles of 64 (4096/64)
#define TSLAB 16384            // shorts per (tile256, ktile64): 256 rows * 64 k

typedef short short8 __attribute__((ext_vector_type(8)));   // 8 bf16
typedef float floatx4 __attribute__((ext_vector_type(4)));

// f32 -> bf16, round-to-nearest-even
__device__ __forceinline__ unsigned short f2bf(float f) {
  union { float f; uint32_t u; } c; c.f = f;
  uint32_t u = c.u;
  return (unsigned short)((u + 0x7FFFu + ((u >> 16) & 1u)) >> 16);
}

__device__ __forceinline__ float load_sc(const void* p, size_t idx, bool is_f32) {
  if (is_f32) return ((const float*)p)[idx];
  return __half2float(((const __half*)p)[idx]);
}

// ---- dtype sniffs (verified rounds 2-12) ----
__device__ __forceinline__ bool sniff_q_is_i32(const void* qv) {
  const int* w = (const int*)qv;
  bool ok = true;
  #pragma unroll
  for (int j = 0; j < 16; ++j) {
    int v = w[j];
    ok = ok && (v == (int)(signed char)(v & 0xFF));
  }
  return ok;
}
__device__ __forceinline__ bool sniff_s_is_f32(const void* sv) {
  const float* f = (const float*)sv;
  bool ok = true;
  #pragma unroll
  for (int j = 0; j < 8; ++j) {
    float v = f[j];
    ok = ok && (v > 4e-4f) && (v < 6e-2f);
  }
  return ok;
}

// async global -> LDS, 16B per lane (dest = wave-uniform base + lane*16)
__device__ __forceinline__ void gload_lds16(const short* g, short* l) {
  __builtin_amdgcn_global_load_lds(
      (const __attribute__((address_space(1))) uint32_t*)g,
      (__attribute__((address_space(3))) uint32_t*)l, 16, 0, 0);
}

// ============ fused prep: W-dequant rows then x-convert rows ============
// Layout (both): [tile256][ktile64][TSLAB]; element (r, k64):
//   r*64 + ((k64/8) ^ (r&7))*8 + (k64%8)   -- slot swizzle, 2-way-free reads.
// One block per output row; thread t covers k = t*16 .. t*16+15.
__global__ __launch_bounds__(256)
void prep_fused(const float* __restrict__ x, const void* __restrict__ qv,
                const void* __restrict__ sv,
                short* __restrict__ xh, short* __restrict__ wq) {
  const int tid = threadIdx.x;
  const int b = blockIdx.x;
  const int ktile = tid >> 2;
  const int s0 = (tid & 3) * 2;          // k8 slot base (0,2,4,6)
  const int k0 = ktile * 64 + s0 * 8;

  if (b < N_DIM) {
    // ---- W dequant: row o = b ----
    const bool q_is_i32 = sniff_q_is_i32(qv);
    const bool s_is_f32 = sniff_s_is_f32(sv);
    const int o = b;
    const int nt = o >> 8, r = o & 255;

    const float s = load_sc(sv, (size_t)o * 64 + ktile, s_is_f32);  // GROUP=64

    int codes[16];
    if (q_is_i32) {
      const int* qq = (const int*)qv + (size_t)o * K_DIM + k0;
      #pragma unroll
      for (int j = 0; j < 4; ++j) {
        int4 t = ((const int4*)qq)[j];
        codes[j*4+0]=t.x; codes[j*4+1]=t.y; codes[j*4+2]=t.z; codes[j*4+3]=t.w;
      }
    } else {
      union { int4 v; int8_t c[16]; } u;
      u.v = *(const int4*)((const int8_t*)qv + (size_t)o * K_DIM + k0);
      #pragma unroll
      for (int j = 0; j < 16; ++j) codes[j] = (int)u.c[j];
    }

    short8 h0, h1;
    #pragma unroll
    for (int j = 0; j < 8; ++j) h0[j] = f2bf((float)codes[j] * s);
    #pragma unroll
    for (int j = 0; j < 8; ++j) h1[j] = f2bf((float)codes[8 + j] * s);

    short* slab = wq + ((size_t)nt * KT64 + ktile) * TSLAB;
    const int sl0 = s0 ^ (r & 7);
    *(short8*)&slab[r * 64 + sl0 * 8]       = h0;
    *(short8*)&slab[r * 64 + (sl0 ^ 1) * 8] = h1;
  } else {
    // ---- x convert: row m = b - N_DIM ----
    const int m = b - N_DIM;
    const int mt = m >> 8, r = m & 255;

    const float4* p = (const float4*)(x + (size_t)m * K_DIM + k0);
    float4 f0 = p[0], f1 = p[1], f2 = p[2], f3 = p[3];
    short8 h0, h1;
    h0[0]=f2bf(f0.x); h0[1]=f2bf(f0.y); h0[2]=f2bf(f0.z); h0[3]=f2bf(f0.w);
    h0[4]=f2bf(f1.x); h0[5]=f2bf(f1.y); h0[6]=f2bf(f1.z); h0[7]=f2bf(f1.w);
    h1[0]=f2bf(f2.x); h1[1]=f2bf(f2.y); h1[2]=f2bf(f2.z); h1[3]=f2bf(f2.w);
    h1[4]=f2bf(f3.x); h1[5]=f2bf(f3.y); h1[6]=f2bf(f3.z); h1[7]=f2bf(f3.w);

    short* slab = xh + ((size_t)mt * KT64 + ktile) * TSLAB;
    const int sl0 = s0 ^ (r & 7);
    *(short8*)&slab[r * 64 + sl0 * 8]       = h0;
    *(short8*)&slab[r * 64 + (sl0 ^ 1) * 8] = h1;
  }
}

// ============ GEMM: 256x256, BK=64, 8 waves, m201 8-phase schedule ==========
__global__ __launch_bounds__(512)
void gemm8(const short* __restrict__ xh, const short* __restrict__ wq,
           const void* __restrict__ sv, const void* __restrict__ bv,
           float* __restrict__ C) {
  __shared__ __align__(16) short lds[2 * 2 * TSLAB];  // 128 KiB: 2 buf x (A,B)

  const bool s_is_f32 = sniff_s_is_f32(sv);

  const int tid  = threadIdx.x;
  const int lane = tid & 63;
  const int wid  = tid >> 6;                  // 8 waves
  const int wm = wid >> 2, wn = wid & 3;      // 2x4 -> 128x64 out per wave
  const int lr = lane & 15, lk = lane >> 4;

  // nt-major dispatch (r6/r8-verified)
  const int bid = blockIdx.x;
  const int xcd = bid & 7;
  const int seq = bid >> 3;                   // [0,172)
  const int nt  = seq >> 2;                   // [0,43)
  const int mt  = xcd * 4 + (seq & 3);        // [0,32)

  const short* Aslab = xh + (size_t)mt * (KT64 * TSLAB);
  const short* Bslab = wq + (size_t)nt * (KT64 * TSLAB);

  // slot terms: slot = (ks*4+lk) ^ (row&7), row&7 == lr&7 (bases mult of 16)
  int sk[2];
  sk[0] = (lk ^ (lr & 7)) * 8;
  sk[1] = sk[0] ^ 32;

  floatx4 acc[8][4];
  #pragma unroll
  for (int i = 0; i < 8; ++i)
    #pragma unroll
    for (int j = 0; j < 4; ++j)
      acc[i][j] = (floatx4){0.f, 0.f, 0.f, 0.f};

  short8 a[2][4], b0[2][2], b1[2][2];   // quadrant register sets (static idx)

#define SBAR __builtin_amdgcn_sched_barrier(0)
#define VMCNT(n) do { asm volatile("s_waitcnt vmcnt(" #n ")"); SBAR; } while (0)
#define LGKM0 do { asm volatile("s_waitcnt lgkmcnt(0)"); SBAR; } while (0)
#define BARRIER do { SBAR; __builtin_amdgcn_s_barrier(); SBAR; } while (0)

#define STAGE_A(t, h) do {                                              \
    const short* g_ = Aslab + (size_t)(t) * TSLAB + (h) * 8192;         \
    short* l_ = lds + ((t) & 1) * (2 * TSLAB) + (h) * 8192;             \
    gload_lds16(g_ + tid * 8,        l_ + tid * 8);                     \
    gload_lds16(g_ + 4096 + tid * 8, l_ + 4096 + tid * 8);              \
  } while (0)

#define STAGE_B(t, h) do {                                              \
    const short* g_ = Bslab + (size_t)(t) * TSLAB + (h) * 8192;         \
    short* l_ = lds + ((t) & 1) * (2 * TSLAB) + TSLAB + (h) * 8192;     \
    gload_lds16(g_ + tid * 8,        l_ + tid * 8);                     \
    gload_lds16(g_ + 4096 + tid * 8, l_ + 4096 + tid * 8);              \
  } while (0)

#define READS_A(mh, t) do {                                             \
    const short* lA_ = lds + ((t) & 1) * (2 * TSLAB);                   \
    _Pragma("unroll")                                                   \
    for (int ks = 0; ks < 2; ++ks)                                      \
      _Pragma("unroll")                                                 \
      for (int mi = 0; mi < 4; ++mi)                                    \
        a[ks][mi] = *(const short8*)&lA_[                               \
            (wm * 128 + (mh) * 64 + mi * 16 + lr) * 64 + sk[ks]];       \
  } while (0)

#define READS_B(dst, nh, t) do {                                        \
    const short* lB_ = lds + ((t) & 1) * (2 * TSLAB) + TSLAB;           \
    _Pragma("unroll")                                                   \
    for (int ks = 0; ks < 2; ++ks)                                      \
      _Pragma("unroll")                                                 \
      for (int ni = 0; ni < 2; ++ni)                                    \
        dst[ks][ni] = *(const short8*)&lB_[                             \
            (wn * 64 + (nh) * 32 + ni * 16 + lr) * 64 + sk[ks]];        \
  } while (0)

#define MFMA_Q(mh, nh, bs) do {                                         \
    __builtin_amdgcn_s_setprio(1);                                      \
    _Pragma("unroll")                                                   \
    for (int mi = 0; mi < 4; ++mi)                                      \
      _Pragma("unroll")                                                 \
      for (int ni = 0; ni < 2; ++ni) {                                  \
        acc[(mh)*4+mi][(nh)*2+ni] = __builtin_amdgcn_mfma_f32_16x16x32_bf16( \
            a[0][mi], bs[0][ni], acc[(mh)*4+mi][(nh)*2+ni], 0, 0, 0);   \
        acc[(mh)*4+mi][(nh)*2+ni] = __builtin_amdgcn_mfma_f32_16x16x32_bf16( \
            a[1][mi], bs[1][ni], acc[(mh)*4+mi][(nh)*2+ni], 0, 0, 0);   \
      }                                                                 \
    __builtin_amdgcn_s_setprio(0);                                      \
  } while (0)

  // prologue (virtual iter -1, ph3-8): B(0), A(0), B(1) halves = 12 loads;
  // VMCNT(4) retires through Ah1(0) = tile 0 complete; barrier publishes.
  STAGE_B(0, 0); STAGE_B(0, 1);
  STAGE_A(0, 0); STAGE_A(0, 1);
  STAGE_B(1, 0); STAGE_B(1, 1);
  VMCNT(4);
  BARRIER;

  // Main loop: 31 iters (tiles 0..61), each = 2 K-tiles, 8 phases.
  // Stage slots per iter i: ph1 Ah0(2i+1), ph2 Ah1(2i+1), ph3 Bh0(2i+2),
  // ph4 Bh1(2i+2), ph5 Ah0(2i+2), ph6 Ah1(2i+2), ph7 Bh0(2i+3), ph8 Bh1(2i+3)
  // -- each target's reads retired >=1 barrier earlier. VMCNT(4) at ph4
  // publishes tile 2i+1; at ph8 publishes tile 2i+2.
  for (int t0 = 0; t0 < 62; t0 += 2) {
    const int t1 = t0 + 1;
    // ph1: quadrant (0,0) of t0
    READS_A(0, t0); READS_B(b0, 0, t0);
    STAGE_A(t0 + 1, 0);
    BARRIER; LGKM0;
    MFMA_Q(0, 0, b0);
    BARRIER;
    // ph2: (0,1)
    READS_B(b1, 1, t0);
    STAGE_A(t0 + 1, 1);
    BARRIER; LGKM0;
    MFMA_Q(0, 1, b1);
    BARRIER;
    // ph3: (1,1)
    READS_A(1, t0);
    STAGE_B(t0 + 2, 0);
    BARRIER; LGKM0;
    MFMA_Q(1, 1, b1);
    BARRIER;
    // ph4: (1,0) -- publish tile t1
    STAGE_B(t0 + 2, 1);
    VMCNT(4);
    BARRIER;
    MFMA_Q(1, 0, b0);
    BARRIER;
    // ph5: quadrant (0,0) of t1
    READS_A(0, t1); READS_B(b0, 0, t1);
    STAGE_A(t0 + 2, 0);
    BARRIER; LGKM0;
    MFMA_Q(0, 0, b0);
    BARRIER;
    // ph6: (0,1)
    READS_B(b1, 1, t1);
    STAGE_A(t0 + 2, 1);
    BARRIER; LGKM0;
    MFMA_Q(0, 1, b1);
    BARRIER;
    // ph7: (1,1)
    READS_A(1, t1);
    STAGE_B(t0 + 3, 0);
    BARRIER; LGKM0;
    MFMA_Q(1, 1, b1);
    BARRIER;
    // ph8: (1,0) -- publish tile t0+2
    STAGE_B(t0 + 3, 1);
    VMCNT(4);
    BARRIER;
    MFMA_Q(1, 0, b0);
    BARRIER;
  }

  // peeled last iteration: tiles 62,63. Ah(63) still staged (real); no
  // stages for 64/65. At ph4: in-flight = Bh(63) 4 + Ah(63) 4 -> VMCNT(0).
  READS_A(0, 62); READS_B(b0, 0, 62);
  STAGE_A(63, 0);
  BARRIER; LGKM0;
  MFMA_Q(0, 0, b0);
  BARRIER;
  READS_B(b1, 1, 62);
  STAGE_A(63, 1);
  BARRIER; LGKM0;
  MFMA_Q(0, 1, b1);
  BARRIER;
  READS_A(1, 62);
  BARRIER; LGKM0;
  MFMA_Q(1, 1, b1);
  BARRIER;
  VMCNT(0);
  BARRIER;                      // publish tile 63
  MFMA_Q(1, 0, b0);
  BARRIER;
  READS_A(0, 63); READS_B(b0, 0, 63);
  BARRIER; LGKM0;
  MFMA_Q(0, 0, b0);
  BARRIER;
  READS_B(b1, 1, 63);
  BARRIER; LGKM0;
  MFMA_Q(0, 1, b1);
  BARRIER;
  READS_A(1, 63);
  BARRIER; LGKM0;
  MFMA_Q(1, 1, b1);
  MFMA_Q(1, 0, b0);

#undef STAGE_A
#undef STAGE_B
#undef READS_A
#undef READS_B
#undef MFMA_Q
#undef SBAR
#undef VMCNT
#undef LGKM0
#undef BARRIER

  // epilogue: acc[L][nc], L = mh*4+mi -> row offset (L>>2)*64 + (L&3)*16;
  // C/D layout col = lane&15, row = (lane>>4)*4 + reg (verified r2-r12)
  #pragma unroll
  for (int nc = 0; nc < 4; ++nc) {
    const int col = nt * 256 + wn * 64 + nc * 16 + lr;
    const float bvf = load_sc(bv, (size_t)col, s_is_f32);
    #pragma unroll
    for (int L = 0; L < 8; ++L) {
      const int rbase = mt * 256 + wm * 128 + (L >> 2) * 64 + (L & 3) * 16 + lk * 4;
      #pragma unroll
      for (int rr = 0; rr < 4; ++rr)
        C[(size_t)(rbase + rr) * N_DIM + col] = acc[L][nc][rr] + bvf;
    }
  }
}

// ============ fallback: round-2-verified fully fused kernel ============
__global__ __launch_bounds__(256)
void gemm_fused(const float* __restrict__ x, const void* __restrict__ qv,
                const void* __restrict__ sv, const void* __restrict__ bv,
                float* __restrict__ C) {
  __shared__ __align__(16) short As[128 * 64];
  __shared__ __align__(16) short Bs[128 * 64];

  const bool q_is_i32 = sniff_q_is_i32(qv);
  const bool s_is_f32 = sniff_s_is_f32(sv);

  const int tid  = threadIdx.x;
  const int lane = tid & 63;
  const int wid  = tid >> 6;
  const int wm = wid >> 1, wn = wid & 1;
  const int lr = lane & 15, lk = lane >> 4;

  const int nwg = gridDim.x;
  const int cpx = nwg >> 3;
  const int bid = blockIdx.x;
  const int swz = (bid & 7) * cpx + (bid >> 3);
  const int per_g = 4 * 86;
  const int g = swz / per_g;
  const int r = swz - g * per_g;
  const int mt = (g << 2) + (r & 3);
  const int nt = r >> 2;

  const int row0 = mt * 128;
  const int col0 = nt * 128;

  floatx4 acc[4][4];
  #pragma unroll
  for (int i = 0; i < 4; ++i)
    #pragma unroll
    for (int j = 0; j < 4; ++j)
      acc[i][j] = (floatx4){0.f, 0.f, 0.f, 0.f};

  for (int kt = 0; kt < K_DIM / 64; ++kt) {
    const int k0 = kt * 64;
    #pragma unroll
    for (int i = 0; i < 4; ++i) {
      const int cid = i * 256 + tid;
      const int arow = cid >> 3, ac = (cid & 7) << 3;
      const float4* p = (const float4*)(x + (size_t)(row0 + arow) * K_DIM + k0 + ac);
      float4 a = p[0], b = p[1];
      short8 h;
      h[0]=f2bf(a.x); h[1]=f2bf(a.y); h[2]=f2bf(a.z); h[3]=f2bf(a.w);
      h[4]=f2bf(b.x); h[5]=f2bf(b.y); h[6]=f2bf(b.z); h[7]=f2bf(b.w);
      *(short8*)&As[arow * 64 + ac] = h;
    }
    #pragma unroll
    for (int i = 0; i < 2; ++i) {
      const int cid = i * 256 + tid;
      const int brow = cid >> 2, bc = (cid & 3) << 4;
      const float s = load_sc(sv, (size_t)(col0 + brow) * 64 + kt, s_is_f32);
      int codes[16];
      if (q_is_i32) {
        const int* qq = (const int*)qv + (size_t)(col0 + brow) * K_DIM + k0 + bc;
        #pragma unroll
        for (int j = 0; j < 4; ++j) {
          int4 t = ((const int4*)qq)[j];
          codes[j*4+0]=t.x; codes[j*4+1]=t.y; codes[j*4+2]=t.z; codes[j*4+3]=t.w;
        }
      } else {
        union { int4 v; int8_t c[16]; } u;
        u.v = *(const int4*)((const int8_t*)qv + (size_t)(col0 + brow) * K_DIM + k0 + bc);
        #pragma unroll
        for (int j = 0; j < 16; ++j) codes[j] = (int)u.c[j];
      }
      short8 h0, h1;
      #pragma unroll
      for (int j = 0; j < 8; ++j) h0[j] = f2bf((float)codes[j] * s);
      #pragma unroll
      for (int j = 0; j < 8; ++j) h1[j] = f2bf((float)codes[8 + j] * s);
      *(short8*)&Bs[brow * 64 + bc]     = h0;
      *(short8*)&Bs[brow * 64 + bc + 8] = h1;
    }
    __syncthreads();
    #pragma unroll
    for (int ks = 0; ks < 2; ++ks) {
      short8 a[4], b[4];
      #pragma unroll
      for (int mi = 0; mi < 4; ++mi)
        a[mi] = *(const short8*)&As[(wm * 64 + mi * 16 + lr) * 64 + ks * 32 + lk * 8];
      #pragma unroll
      for (int ni = 0; ni < 4; ++ni)
        b[ni] = *(const short8*)&Bs[(wn * 64 + ni * 16 + lr) * 64 + ks * 32 + lk * 8];
      #pragma unroll
      for (int mi = 0; mi < 4; ++mi)
        #pragma unroll
        for (int ni = 0; ni < 4; ++ni)
          acc[mi][ni] = __builtin_amdgcn_mfma_f32_16x16x32_bf16(
              a[mi], b[ni], acc[mi][ni], 0, 0, 0);
    }
    __syncthreads();
  }

  #pragma unroll
  for (int ni = 0; ni < 4; ++ni) {
    const int col = col0 + wn * 64 + ni * 16 + lr;
    const float bvf = load_sc(bv, (size_t)col, s_is_f32);
    #pragma unroll
    for (int mi = 0; mi < 4; ++mi) {
      const int rbase = row0 + wm * 64 + mi * 16 + lk * 4;
      #pragma unroll
      for (int rr = 0; rr < 4; ++rr)
        C[(size_t)(rbase + rr) * N_DIM + col] = acc[mi][ni][rr] + bvf;
    }
  }
}

extern "C" void kernel_launch(void* const* d_in, const int* in_sizes, int n_in,
                              void* d_out, int out_size, void* d_ws, size_t ws_size,
                              hipStream_t stream) {
  const float* x  = (const float*)d_in[0];
  const void*  q  = (const void*)d_in[1];
  const void*  sc = (const void*)d_in[2];
  const void*  bs = (const void*)d_in[3];
  float* y = (float*)d_out;
  (void)in_sizes; (void)n_in; (void)out_size;

  const size_t xh_bytes = (size_t)M_DIM * K_DIM * 2;   // 64 MiB
  const size_t wq_bytes = (size_t)N_DIM * K_DIM * 2;   // ~86 MiB

  if (ws_size >= xh_bytes + wq_bytes) {   // confirmed available (r3-r12)
    short* xh = (short*)d_ws;
    short* wq = (short*)((char*)d_ws + xh_bytes);
    prep_fused<<<N_DIM + M_DIM, dim3(256), 0, stream>>>(x, q, sc, xh, wq);
    gemm8<<<MT_TILES * NT_TILES, dim3(512), 0, stream>>>(xh, wq, sc, bs, y);
  } else {
    gemm_fused<<<(M_DIM / 128) * (N_DIM / 128), dim3(256), 0, stream>>>(x, q, sc, bs, y);
  }
}

// Round 14
// 748.441 us; speedup vs baseline: 1.0408x; 1.0050x over previous
//
#include <hip/hip_runtime.h>
#include <hip/hip_fp16.h>
#include <stdint.h>

// PrunedInt4Linear: y = x @ dequant(q, scales)^T + bias
// Round 14: 2 blocks/CU. Six schedules all pinned at ~2400 cyc/K-step because
// 1 block/CU locksteps all 8 waves at each barrier -> LDS and MFMA phases
// strictly alternate (serial sum = measured). Fix: 256-thread blocks (4
// waves), tile 128x256, LDS 72 KiB (3-deep ring) -> 2 independent barrier
// groups per CU; one block's MFMA overlaps the other's LDS phase (m114).
// Same 256-reg/wave footprint (8 waves/CU), same proven ws layouts + prep.

#define M_DIM 8192
#define N_DIM 11008
#define K_DIM 4096
#define MT_TILES 64            // 8192 / 128  (M-tile now 128)
#define NT_TILES 43            // 11008 / 256
#define K_TILES 128            // 4096 / 32
#define SLAB 8192              // shorts per 256-row, 32-k ws slab (unchanged)
#define RSTRIDE 12288          // shorts per LDS ring slot: A 4096 + B 8192

typedef short short8 __attribute__((ext_vector_type(8)));   // 8 bf16
typedef float floatx4 __attribute__((ext_vector_type(4)));

// f32 -> bf16, round-to-nearest-even
__device__ __forceinline__ unsigned short f2bf(float f) {
  union { float f; uint32_t u; } c; c.f = f;
  uint32_t u = c.u;
  return (unsigned short)((u + 0x7FFFu + ((u >> 16) & 1u)) >> 16);
}

__device__ __forceinline__ float load_sc(const void* p, size_t idx, bool is_f32) {
  if (is_f32) return ((const float*)p)[idx];
  return __half2float(((const __half*)p)[idx]);
}

// ---- dtype sniffs (verified rounds 2-13) ----
__device__ __forceinline__ bool sniff_q_is_i32(const void* qv) {
  const int* w = (const int*)qv;
  bool ok = true;
  #pragma unroll
  for (int j = 0; j < 16; ++j) {
    int v = w[j];
    ok = ok && (v == (int)(signed char)(v & 0xFF));
  }
  return ok;
}
__device__ __forceinline__ bool sniff_s_is_f32(const void* sv) {
  const float* f = (const float*)sv;
  bool ok = true;
  #pragma unroll
  for (int j = 0; j < 8; ++j) {
    float v = f[j];
    ok = ok && (v > 4e-4f) && (v < 6e-2f);
  }
  return ok;
}

// async global -> LDS, 16B per lane (dest = wave-uniform base + lane*16)
__device__ __forceinline__ void gload_lds16(const short* g, short* l) {
  __builtin_amdgcn_global_load_lds(
      (const __attribute__((address_space(1))) uint32_t*)g,
      (__attribute__((address_space(3))) uint32_t*)l, 16, 0, 0);
}

// ============ fused prep (r8/r12-verified, UNCHANGED) ============
// xh: [mt32 256-row][kt 128][slab]; (r,k): r*32 + ((k/8) ^ ((r>>1)&3))*8 + k%8
// wq: [nt 43][kt 128][slab]; same within-slab swizzle
__global__ __launch_bounds__(256)
void prep_fused(const float* __restrict__ x, const void* __restrict__ qv,
                const void* __restrict__ sv,
                short* __restrict__ xh, short* __restrict__ wq) {
  const int tid = threadIdx.x;
  int b = blockIdx.x;

  if (b < NT_TILES * 256) {
    // ---- W dequant ----
    const bool q_is_i32 = sniff_q_is_i32(qv);
    const bool s_is_f32 = sniff_s_is_f32(sv);
    const int nt = b >> 8;
    const int rem = b & 255;
    const int kt = rem >> 1, half = rem & 1;
    const int r = half * 128 + (tid >> 1);
    const int s0 = (tid & 1) * 2;
    const int o = nt * 256 + r;
    const int k0 = kt * 32 + s0 * 8;

    const float s = load_sc(sv, (size_t)o * 64 + (kt >> 1), s_is_f32);

    int codes[16];
    if (q_is_i32) {
      const int* qq = (const int*)qv + (size_t)o * K_DIM + k0;
      #pragma unroll
      for (int j = 0; j < 4; ++j) {
        int4 t = ((const int4*)qq)[j];
        codes[j*4+0]=t.x; codes[j*4+1]=t.y; codes[j*4+2]=t.z; codes[j*4+3]=t.w;
      }
    } else {
      union { int4 v; int8_t c[16]; } u;
      u.v = *(const int4*)((const int8_t*)qv + (size_t)o * K_DIM + k0);
      #pragma unroll
      for (int j = 0; j < 16; ++j) codes[j] = (int)u.c[j];
    }

    short8 h0, h1;
    #pragma unroll
    for (int j = 0; j < 8; ++j) h0[j] = f2bf((float)codes[j] * s);
    #pragma unroll
    for (int j = 0; j < 8; ++j) h1[j] = f2bf((float)codes[8 + j] * s);

    const int w = (r >> 1) & 3;
    short* slab = wq + ((size_t)nt * K_TILES + kt) * SLAB;
    *(short8*)&slab[r * 32 + ((s0    ) ^ w) * 8] = h0;
    *(short8*)&slab[r * 32 + ((s0 + 1) ^ w) * 8] = h1;
  } else {
    // ---- x convert ----
    b -= NT_TILES * 256;
    const int mt = b >> 8;
    const int rem = b & 255;
    const int kt = rem >> 1, half = rem & 1;
    const int r = half * 128 + (tid >> 1);
    const int s0 = (tid & 1) * 2;
    const int k0 = kt * 32 + s0 * 8;

    const float4* p = (const float4*)(x + (size_t)(mt * 256 + r) * K_DIM + k0);
    float4 f0 = p[0], f1 = p[1], f2 = p[2], f3 = p[3];
    short8 h0, h1;
    h0[0]=f2bf(f0.x); h0[1]=f2bf(f0.y); h0[2]=f2bf(f0.z); h0[3]=f2bf(f0.w);
    h0[4]=f2bf(f1.x); h0[5]=f2bf(f1.y); h0[6]=f2bf(f1.z); h0[7]=f2bf(f1.w);
    h1[0]=f2bf(f2.x); h1[1]=f2bf(f2.y); h1[2]=f2bf(f2.z); h1[3]=f2bf(f2.w);
    h1[4]=f2bf(f3.x); h1[5]=f2bf(f3.y); h1[6]=f2bf(f3.z); h1[7]=f2bf(f3.w);

    const int w = (r >> 1) & 3;
    short* slab = xh + ((size_t)mt * K_TILES + kt) * SLAB;
    *(short8*)&slab[r * 32 + ((s0    ) ^ w) * 8] = h0;
    *(short8*)&slab[r * 32 + ((s0 + 1) ^ w) * 8] = h1;
  }
}

// ============ GEMM: 128x256 tile, BK=32, 4 waves, 2 blocks/CU ============
__global__ __launch_bounds__(256, 2)
void gemm4(const short* __restrict__ xh, const short* __restrict__ wq,
           const void* __restrict__ sv, const void* __restrict__ bv,
           float* __restrict__ C) {
  __shared__ __align__(16) short lds[3 * RSTRIDE];   // 72 KiB: 3-deep ring

  const bool s_is_f32 = sniff_s_is_f32(sv);

  const int tid  = threadIdx.x;
  const int lane = tid & 63;
  const int wid  = tid >> 6;                  // 4 waves
  const int wm = wid >> 1, wn = wid & 1;      // 2x2 -> 64x128 out per wave
  const int lr = lane & 15, lk = lane >> 4;

  // nt-major XCD dispatch: 2752 = 8 * 344, 344 = 43 * 8 (bijective)
  const int bid = blockIdx.x;
  const int xcd = bid & 7;
  const int seq = bid >> 3;                   // [0,344)
  const int nt  = seq >> 3;                   // [0,43)
  const int mt  = xcd * 8 + (seq & 7);        // [0,64) (128-row tiles)

  // A = 128-row half of the 256-row ws slab (contiguous; swizzle invariant)
  const short* Aslab = xh + (size_t)(mt >> 1) * (K_TILES * SLAB) + (mt & 1) * 4096;
  const short* Bslab = wq + (size_t)nt * (K_TILES * SLAB);

  // fragment LDS offsets (r4-verified swizzle, 0 conflicts)
  const int swz8 = (lk ^ ((lr >> 1) & 3)) << 3;
  int aoff[4], boff[8];
  #pragma unroll
  for (int mi = 0; mi < 4; ++mi) aoff[mi] = (wm * 64 + mi * 16 + lr) * 32 + swz8;
  #pragma unroll
  for (int ni = 0; ni < 8; ++ni) boff[ni] = (wn * 128 + ni * 16 + lr) * 32 + swz8;

  floatx4 acc[4][8];
  #pragma unroll
  for (int i = 0; i < 4; ++i)
    #pragma unroll
    for (int j = 0; j < 8; ++j)
      acc[i][j] = (floatx4){0.f, 0.f, 0.f, 0.f};

  short8 fa[4], fb[8], ga[4], gb[8];   // two named frag sets (rule #20)

#define SBAR __builtin_amdgcn_sched_barrier(0)
#define VMCNT(n) do { asm volatile("s_waitcnt vmcnt(" #n ")"); SBAR; } while (0)
#define LGKM0 do { asm volatile("s_waitcnt lgkmcnt(0)"); SBAR; } while (0)
#define BARRIER do { SBAR; __builtin_amdgcn_s_barrier(); SBAR; } while (0)

// stage = 6 loads: A half-slab 8 KB (2) + B slab 16 KB (4)
#define STAGE(t) do {                                                   \
    const int s_ = (t) % 3;                                             \
    const short* gA_ = Aslab + (size_t)(t) * SLAB;                      \
    const short* gB_ = Bslab + (size_t)(t) * SLAB;                      \
    short* lA_ = lds + s_ * RSTRIDE;                                    \
    short* lB_ = lA_ + 4096;                                            \
    gload_lds16(gA_ + tid * 8,        lA_ + tid * 8);                   \
    gload_lds16(gA_ + 2048 + tid * 8, lA_ + 2048 + tid * 8);            \
    gload_lds16(gB_ + tid * 8,        lB_ + tid * 8);                   \
    gload_lds16(gB_ + 2048 + tid * 8, lB_ + 2048 + tid * 8);            \
    gload_lds16(gB_ + 4096 + tid * 8, lB_ + 4096 + tid * 8);            \
    gload_lds16(gB_ + 6144 + tid * 8, lB_ + 6144 + tid * 8);            \
  } while (0)

#define LOADF(da, db, t) do {                                           \
    const short* lA_ = lds + ((t) % 3) * RSTRIDE;                       \
    const short* lB_ = lA_ + 4096;                                      \
    _Pragma("unroll")                                                   \
    for (int mi = 0; mi < 4; ++mi) da[mi] = *(const short8*)&lA_[aoff[mi]]; \
    _Pragma("unroll")                                                   \
    for (int ni = 0; ni < 8; ++ni) db[ni] = *(const short8*)&lB_[boff[ni]]; \
  } while (0)

#define DOMFMA(sa, sb) do {                                             \
    __builtin_amdgcn_s_setprio(1);                                      \
    _Pragma("unroll")                                                   \
    for (int mi = 0; mi < 4; ++mi)                                      \
      _Pragma("unroll")                                                 \
      for (int ni = 0; ni < 8; ++ni)                                    \
        acc[mi][ni] = __builtin_amdgcn_mfma_f32_16x16x32_bf16(          \
            sa[mi], sb[ni], acc[mi][ni], 0, 0, 0);                      \
    __builtin_amdgcn_s_setprio(0);                                      \
  } while (0)

  // prologue: stage 3 tiles (18 loads); retire tile 0; publish; read frags
  STAGE(0); STAGE(1); STAGE(2);
  VMCNT(12);
  BARRIER;
  LOADF(fa, fb, 0);

  // Steady half-iter (tile kt current):
  //   VMCNT(6): outstanding [kt+1(6), kt+2(6)] -> retire kt+1
  //   LGKM0   : drain own ds_reads of slot kt%3 (issued last half-iter)
  //             BEFORE the barrier -> cross-wave safe vs STAGE below
  //   BARRIER : publish tile kt+1 (r6-proven publish-then-read)
  //   STAGE(kt+3): writes slot kt%3 (reads drained pre-barrier by ALL waves)
  //   LOADF(kt+1) overlaps DOMFMA(kt) (regs from last half-iter)
  for (int kt = 0; kt < 124; kt += 2) {
    VMCNT(6);
    LGKM0;
    BARRIER;
    STAGE(kt + 3);
    LOADF(ga, gb, kt + 1);
    DOMFMA(fa, fb);            // tile kt
    VMCNT(6);
    LGKM0;
    BARRIER;
    STAGE(kt + 4);
    LOADF(fa, fb, kt + 2);
    DOMFMA(ga, gb);            // tile kt+1
  }

  // tail: outstanding [125(6),126(6)]; fa holds tile 124 frags
  VMCNT(6);
  LGKM0;
  BARRIER;
  STAGE(127);
  LOADF(ga, gb, 125);
  DOMFMA(fa, fb);              // 124
  VMCNT(6);                    // retire 126
  LGKM0;
  BARRIER;
  LOADF(fa, fb, 126);
  DOMFMA(ga, gb);              // 125
  VMCNT(0);                    // retire 127
  LGKM0;
  BARRIER;
  LOADF(ga, gb, 127);
  DOMFMA(fa, fb);              // 126
  DOMFMA(ga, gb);              // 127

#undef STAGE
#undef LOADF
#undef DOMFMA
#undef SBAR
#undef VMCNT
#undef LGKM0
#undef BARRIER

  // epilogue: C/D layout col = lane&15, row = (lane>>4)*4 + reg (verified)
  #pragma unroll
  for (int ni = 0; ni < 8; ++ni) {
    const int col = nt * 256 + wn * 128 + ni * 16 + lr;
    const float bvf = load_sc(bv, (size_t)col, s_is_f32);
    #pragma unroll
    for (int mi = 0; mi < 4; ++mi) {
      const int rbase = mt * 128 + wm * 64 + mi * 16 + lk * 4;
      #pragma unroll
      for (int rr = 0; rr < 4; ++rr)
        C[(size_t)(rbase + rr) * N_DIM + col] = acc[mi][ni][rr] + bvf;
    }
  }
}

// ============ fallback: round-2-verified fully fused kernel ============
__global__ __launch_bounds__(256)
void gemm_fused(const float* __restrict__ x, const void* __restrict__ qv,
                const void* __restrict__ sv, const void* __restrict__ bv,
                float* __restrict__ C) {
  __shared__ __align__(16) short As[128 * 64];
  __shared__ __align__(16) short Bs[128 * 64];

  const bool q_is_i32 = sniff_q_is_i32(qv);
  const bool s_is_f32 = sniff_s_is_f32(sv);

  const int tid  = threadIdx.x;
  const int lane = tid & 63;
  const int wid  = tid >> 6;
  const int wm = wid >> 1, wn = wid & 1;
  const int lr = lane & 15, lk = lane >> 4;

  const int nwg = gridDim.x;
  const int cpx = nwg >> 3;
  const int bid = blockIdx.x;
  const int swz = (bid & 7) * cpx + (bid >> 3);
  const int per_g = 4 * 86;
  const int g = swz / per_g;
  const int r = swz - g * per_g;
  const int mt = (g << 2) + (r & 3);
  const int nt = r >> 2;

  const int row0 = mt * 128;
  const int col0 = nt * 128;

  floatx4 acc[4][4];
  #pragma unroll
  for (int i = 0; i < 4; ++i)
    #pragma unroll
    for (int j = 0; j < 4; ++j)
      acc[i][j] = (floatx4){0.f, 0.f, 0.f, 0.f};

  for (int kt = 0; kt < K_DIM / 64; ++kt) {
    const int k0 = kt * 64;
    #pragma unroll
    for (int i = 0; i < 4; ++i) {
      const int cid = i * 256 + tid;
      const int arow = cid >> 3, ac = (cid & 7) << 3;
      const float4* p = (const float4*)(x + (size_t)(row0 + arow) * K_DIM + k0 + ac);
      float4 a = p[0], b = p[1];
      short8 h;
      h[0]=f2bf(a.x); h[1]=f2bf(a.y); h[2]=f2bf(a.z); h[3]=f2bf(a.w);
      h[4]=f2bf(b.x); h[5]=f2bf(b.y); h[6]=f2bf(b.z); h[7]=f2bf(b.w);
      *(short8*)&As[arow * 64 + ac] = h;
    }
    #pragma unroll
    for (int i = 0; i < 2; ++i) {
      const int cid = i * 256 + tid;
      const int brow = cid >> 2, bc = (cid & 3) << 4;
      const float s = load_sc(sv, (size_t)(col0 + brow) * 64 + kt, s_is_f32);
      int codes[16];
      if (q_is_i32) {
        const int* qq = (const int*)qv + (size_t)(col0 + brow) * K_DIM + k0 + bc;
        #pragma unroll
        for (int j = 0; j < 4; ++j) {
          int4 t = ((const int4*)qq)[j];
          codes[j*4+0]=t.x; codes[j*4+1]=t.y; codes[j*4+2]=t.z; codes[j*4+3]=t.w;
        }
      } else {
        union { int4 v; int8_t c[16]; } u;
        u.v = *(const int4*)((const int8_t*)qv + (size_t)(col0 + brow) * K_DIM + k0 + bc);
        #pragma unroll
        for (int j = 0; j < 16; ++j) codes[j] = (int)u.c[j];
      }
      short8 h0, h1;
      #pragma unroll
      for (int j = 0; j < 8; ++j) h0[j] = f2bf((float)codes[j] * s);
      #pragma unroll
      for (int j = 0; j < 8; ++j) h1[j] = f2bf((float)codes[8 + j] * s);
      *(short8*)&Bs[brow * 64 + bc]     = h0;
      *(short8*)&Bs[brow * 64 + bc + 8] = h1;
    }
    __syncthreads();
    #pragma unroll
    for (int ks = 0; ks < 2; ++ks) {
      short8 a[4], b[4];
      #pragma unroll
      for (int mi = 0; mi < 4; ++mi)
        a[mi] = *(const short8*)&As[(wm * 64 + mi * 16 + lr) * 64 + ks * 32 + lk * 8];
      #pragma unroll
      for (int ni = 0; ni < 4; ++ni)
        b[ni] = *(const short8*)&Bs[(wn * 64 + ni * 16 + lr) * 64 + ks * 32 + lk * 8];
      #pragma unroll
      for (int mi = 0; mi < 4; ++mi)
        #pragma unroll
        for (int ni = 0; ni < 4; ++ni)
          acc[mi][ni] = __builtin_amdgcn_mfma_f32_16x16x32_bf16(
              a[mi], b[ni], acc[mi][ni], 0, 0, 0);
    }
    __syncthreads();
  }

  #pragma unroll
  for (int ni = 0; ni < 4; ++ni) {
    const int col = col0 + wn * 64 + ni * 16 + lr;
    const float bvf = load_sc(bv, (size_t)col, s_is_f32);
    #pragma unroll
    for (int mi = 0; mi < 4; ++mi) {
      const int rbase = row0 + wm * 64 + mi * 16 + lk * 4;
      #pragma unroll
      for (int rr = 0; rr < 4; ++rr)
        C[(size_t)(rbase + rr) * N_DIM + col] = acc[mi][ni][rr] + bvf;
    }
  }
}

extern "C" void kernel_launch(void* const* d_in, const int* in_sizes, int n_in,
                              void* d_out, int out_size, void* d_ws, size_t ws_size,
                              hipStream_t stream) {
  const float* x  = (const float*)d_in[0];
  const void*  q  = (const void*)d_in[1];
  const void*  sc = (const void*)d_in[2];
  const void*  bs = (const void*)d_in[3];
  float* y = (float*)d_out;
  (void)in_sizes; (void)n_in; (void)out_size;

  const size_t xh_bytes = (size_t)M_DIM * K_DIM * 2;   // 64 MiB
  const size_t wq_bytes = (size_t)N_DIM * K_DIM * 2;   // ~86 MiB

  if (ws_size >= xh_bytes + wq_bytes) {   // confirmed available (r3-r13)
    short* xh = (short*)d_ws;
    short* wq = (short*)((char*)d_ws + xh_bytes);
    prep_fused<<<NT_TILES * 256 + (M_DIM / 256) * 256, dim3(256), 0, stream>>>(
        x, q, sc, xh, wq);
    gemm4<<<MT_TILES * NT_TILES, dim3(256), 0, stream>>>(xh, wq, sc, bs, y);
  } else {
    gemm_fused<<<(M_DIM / 128) * (N_DIM / 128), dim3(256), 0, stream>>>(x, q, sc, bs, y);
  }
}